// Round 8
// baseline (1081.235 us; speedup 1.0000x reference)
//
#include <hip/hip_runtime.h>
#include <stdint.h>

typedef __bf16 bf16x8 __attribute__((ext_vector_type(8)));
typedef float  floatx4 __attribute__((ext_vector_type(4)));

#define T_LEN 512
#define BT    16
#define NTHR  512     // 8 waves; waves 0-3 = layer0, waves 4-7 = layer1
#define XS    72      // xb row stride (bf16)
#define HBS   136     // h bf16 LDS row stride (272B: 16B-aligned rows)
#define HFS   132     // final h1 fp32 row stride

#if __has_builtin(__builtin_amdgcn_exp2f)
#define EXP2(x) __builtin_amdgcn_exp2f(x)
#else
#define EXP2(x) exp2f(x)
#endif

#define MFMA(a,b,c) __builtin_amdgcn_mfma_f32_16x16x32_bf16((a),(b),(c),0,0,0)

__device__ __forceinline__ float sigm(float x) {
    return __builtin_amdgcn_rcpf(1.f + EXP2(-1.4426950408889634f * x));
}
__device__ __forceinline__ float tanh_fast(float x) {
    return 2.f * __builtin_amdgcn_rcpf(1.f + EXP2(-2.8853900817779268f * x)) - 1.f;
}
__device__ __forceinline__ float gru_h(float pr, float pz, float pin, float phn, float hp) {
    const float r = sigm(pr), z = sigm(pz);
    const float n = tanh_fast(pin + r * phn);
    return n + z * (hp - n);
}
__device__ __forceinline__ bf16x8 wfrag(const float* W, int ldk, int row, int k0) {
    const float* p = W + (size_t)row * ldk + k0;
    bf16x8 r;
    #pragma unroll
    for (int j = 0; j < 8; ++j) r[j] = (__bf16)p[j];
    return r;
}

// One block = 16 batch rows, whole sequence, both layers. Wave-specialized:
// waves 0-3 compute layer0 (2 col-tiles each, 36 weight frags = 144 VGPRs),
// waves 4-7 compute layer1 (2 col-tiles each, 48 frags = 192 VGPRs).
// Weight sets now FIT per-wave -> no AGPR parking/copies, no remat.
// Layer-lag: iteration tt = L0 step tt + L1 step tt-1; ONE barrier per iter.
// Both branches execute identical barrier counts (wave-uniform branch; AMD
// s_barrier is arrival-counting, so differing PCs are fine).
__global__ __launch_bounds__(NTHR, 2) void gru_fused(
    const float* __restrict__ x,
    const float* __restrict__ Wih0, const float* __restrict__ Whh0,
    const float* __restrict__ bih0, const float* __restrict__ bhh0,
    const float* __restrict__ Wih1, const float* __restrict__ Whh1,
    const float* __restrict__ bih1, const float* __restrict__ bhh1,
    const float* __restrict__ Wfc,  const float* __restrict__ bfc,
    float* __restrict__ out)
{
    __shared__ __align__(16) __bf16 xb[2][BT * XS];
    __shared__ __align__(16) __bf16 h0b[2][BT * HBS];
    __shared__ __align__(16) __bf16 h1b[2][BT * HBS];
    __shared__ __align__(16) float  hfin[BT * HFS];

    const int tid  = threadIdx.x;
    const int lane = tid & 63;
    const int ln16 = lane & 15;
    const int quad = lane >> 4;
    const int q8   = quad * 8;
    const int wave = tid >> 6;            // 0..7
    const int wv   = wave & 3;            // index within the layer group
    const int brow = blockIdx.x * BT;

    for (int i = tid; i < BT * HBS; i += NTHR) {
        h0b[0][i] = (__bf16)0.f; h0b[1][i] = (__bf16)0.f;
        h1b[0][i] = (__bf16)0.f; h1b[1][i] = (__bf16)0.f;
    }

    // x staging: 2 floats/thread/step, prefetched one step ahead (all waves)
    const int xrow = tid >> 5;            // 0..15
    const int xi0  = (tid & 31) * 2;      // 0..62
    const float* xbase = x + (size_t)(brow + xrow) * T_LEN * 64 + xi0;
    float2 vx = *(const float2*)xbase;    // x(0)

    float hf[2][4] = {{0.f,0.f,0.f,0.f},{0.f,0.f,0.f,0.f}};

    if (wave < 4) {
        // ================= layer-0 waves: cols [32wv, 32wv+32) =================
        float bR[2], bZ[2], bI[2], bH[2];
        bf16x8 wI[2][3][2], wH[2][3][4];      // 36 frags = 144 VGPRs
        #pragma unroll
        for (int t2 = 0; t2 < 2; ++t2) {
            const int c = wv * 32 + t2 * 16 + ln16;
            bR[t2] = bih0[c]       + bhh0[c];
            bZ[t2] = bih0[128 + c] + bhh0[128 + c];
            bI[t2] = bih0[256 + c];
            bH[t2] = bhh0[256 + c];
            #pragma unroll
            for (int g = 0; g < 3; ++g) {
                const int row = g * 128 + c;
                #pragma unroll
                for (int q = 0; q < 2; ++q) wI[t2][g][q] = wfrag(Wih0, 64, row, q * 32 + q8);
                #pragma unroll
                for (int q = 0; q < 4; ++q) wH[t2][g][q] = wfrag(Whh0, 128, row, q * 32 + q8);
            }
        }

        for (int tt = 0; tt <= T_LEN; ++tt) {
            xb[tt & 1][xrow * XS + xi0]     = (__bf16)vx.x;
            xb[tt & 1][xrow * XS + xi0 + 1] = (__bf16)vx.y;
            const int tn = (tt + 1 < T_LEN) ? tt + 1 : T_LEN - 1;
            vx = *(const float2*)(xbase + (size_t)tn * 64);
            __syncthreads();              // barrier 1 of 1 per iter

            if (tt < T_LEN) {
                const int R = tt & 1, Wn = R ^ 1;
                bf16x8 ax0 = *(const bf16x8*)&xb[R][ln16 * XS + q8];
                bf16x8 ax1 = *(const bf16x8*)&xb[R][ln16 * XS + 32 + q8];
                bf16x8 ah[4];
                #pragma unroll
                for (int q = 0; q < 4; ++q)
                    ah[q] = *(const bf16x8*)&h0b[R][ln16 * HBS + q * 32 + q8];

                #pragma unroll
                for (int t2 = 0; t2 < 2; ++t2) {
                    floatx4 aR  = {bR[t2], bR[t2], bR[t2], bR[t2]};
                    floatx4 aZ  = {bZ[t2], bZ[t2], bZ[t2], bZ[t2]};
                    floatx4 aNi = {bI[t2], bI[t2], bI[t2], bI[t2]};
                    floatx4 aNh = {bH[t2], bH[t2], bH[t2], bH[t2]};
                    aR  = MFMA(ax0, wI[t2][0][0], aR);  aR  = MFMA(ax1, wI[t2][0][1], aR);
                    aZ  = MFMA(ax0, wI[t2][1][0], aZ);  aZ  = MFMA(ax1, wI[t2][1][1], aZ);
                    aNi = MFMA(ax0, wI[t2][2][0], aNi); aNi = MFMA(ax1, wI[t2][2][1], aNi);
                    #pragma unroll
                    for (int q = 0; q < 4; ++q) {
                        aR  = MFMA(ah[q], wH[t2][0][q], aR);
                        aZ  = MFMA(ah[q], wH[t2][1][q], aZ);
                        aNh = MFMA(ah[q], wH[t2][2][q], aNh);
                    }
                    const int cc = wv * 32 + t2 * 16 + ln16;
                    #pragma unroll
                    for (int i = 0; i < 4; ++i) {
                        const float h = gru_h(aR[i], aZ[i], aNi[i], aNh[i], hf[t2][i]);
                        hf[t2][i] = h;
                        h0b[Wn][(quad * 4 + i) * HBS + cc] = (__bf16)h;
                    }
                }
            }
        }
    } else {
        // ================= layer-1 waves: cols [32wv, 32wv+32) =================
        float bR[2], bZ[2], bI[2], bH[2];
        bf16x8 wI[2][3][4], wH[2][3][4];      // 48 frags = 192 VGPRs
        #pragma unroll
        for (int t2 = 0; t2 < 2; ++t2) {
            const int c = wv * 32 + t2 * 16 + ln16;
            bR[t2] = bih1[c]       + bhh1[c];
            bZ[t2] = bih1[128 + c] + bhh1[128 + c];
            bI[t2] = bih1[256 + c];
            bH[t2] = bhh1[256 + c];
            #pragma unroll
            for (int g = 0; g < 3; ++g) {
                const int row = g * 128 + c;
                #pragma unroll
                for (int q = 0; q < 4; ++q) {
                    wI[t2][g][q] = wfrag(Wih1, 128, row, q * 32 + q8);
                    wH[t2][g][q] = wfrag(Whh1, 128, row, q * 32 + q8);
                }
            }
        }

        for (int tt = 0; tt <= T_LEN; ++tt) {
            xb[tt & 1][xrow * XS + xi0]     = (__bf16)vx.x;
            xb[tt & 1][xrow * XS + xi0 + 1] = (__bf16)vx.y;
            const int tn = (tt + 1 < T_LEN) ? tt + 1 : T_LEN - 1;
            vx = *(const float2*)(xbase + (size_t)tn * 64);
            __syncthreads();              // barrier 1 of 1 per iter (matches L0 path)

            if (tt > 0) {                 // L1 step tt-1
                const int R = tt & 1, Wn = R ^ 1;
                bf16x8 ah[4];             // h0(tt-1): L1's input-side A
                #pragma unroll
                for (int q = 0; q < 4; ++q)
                    ah[q] = *(const bf16x8*)&h0b[R][ln16 * HBS + q * 32 + q8];

                #pragma unroll
                for (int t2 = 0; t2 < 2; ++t2) {
                    floatx4 aR  = {bR[t2], bR[t2], bR[t2], bR[t2]};
                    floatx4 aZ  = {bZ[t2], bZ[t2], bZ[t2], bZ[t2]};
                    floatx4 aNi = {bI[t2], bI[t2], bI[t2], bI[t2]};
                    floatx4 aNh = {bH[t2], bH[t2], bH[t2], bH[t2]};
                    #pragma unroll
                    for (int q = 0; q < 4; ++q) {
                        aR  = MFMA(ah[q], wI[t2][0][q], aR);
                        aZ  = MFMA(ah[q], wI[t2][1][q], aZ);
                        aNi = MFMA(ah[q], wI[t2][2][q], aNi);
                    }
                    #pragma unroll
                    for (int q = 0; q < 4; ++q) {   // stream h1 A-frags (low pressure)
                        bf16x8 a1 = *(const bf16x8*)&h1b[R][ln16 * HBS + q * 32 + q8];
                        aR  = MFMA(a1, wH[t2][0][q], aR);
                        aZ  = MFMA(a1, wH[t2][1][q], aZ);
                        aNh = MFMA(a1, wH[t2][2][q], aNh);
                    }
                    const int cc = wv * 32 + t2 * 16 + ln16;
                    #pragma unroll
                    for (int i = 0; i < 4; ++i) {
                        const float h = gru_h(aR[i], aZ[i], aNi[i], aNh[i], hf[t2][i]);
                        hf[t2][i] = h;
                        h1b[Wn][(quad * 4 + i) * HBS + cc] = (__bf16)h;
                    }
                }
            }
        }

        // publish final h1 for the FC epilogue
        #pragma unroll
        for (int t2 = 0; t2 < 2; ++t2)
            #pragma unroll
            for (int i = 0; i < 4; ++i)
                hfin[(quad * 4 + i) * HFS + wv * 32 + t2 * 16 + ln16] = hf[t2][i];
    }

    __syncthreads();
    // final FC: out[b] = h1(T-1)[b,:] . Wfc + bfc
    {
        const int row = tid >> 5, l = tid & 31;
        float s = 0.f;
        #pragma unroll
        for (int k = 0; k < 4; ++k)
            s += hfin[row * HFS + l + 32 * k] * Wfc[l + 32 * k];
        #pragma unroll
        for (int d = 16; d >= 1; d >>= 1) s += __shfl_down(s, d, 32);
        if (l == 0) out[brow + row] = s + bfc[0];
    }
}

extern "C" void kernel_launch(void* const* d_in, const int* in_sizes, int n_in,
                              void* d_out, int out_size, void* d_ws, size_t ws_size,
                              hipStream_t stream) {
    const float* x    = (const float*)d_in[0];
    const float* Wih0 = (const float*)d_in[1];
    const float* Whh0 = (const float*)d_in[2];
    const float* bih0 = (const float*)d_in[3];
    const float* bhh0 = (const float*)d_in[4];
    const float* Wih1 = (const float*)d_in[5];
    const float* Whh1 = (const float*)d_in[6];
    const float* bih1 = (const float*)d_in[7];
    const float* bhh1 = (const float*)d_in[8];
    const float* Wfc  = (const float*)d_in[9];
    const float* bfc  = (const float*)d_in[10];
    float* out = (float*)d_out;

    hipLaunchKernelGGL(gru_fused, dim3(512 / BT), dim3(NTHR), 0, stream,
                       x, Wih0, Whh0, bih0, bhh0, Wih1, Whh1, bih1, bhh1, Wfc, bfc, out);
}

// Round 9
// 637.689 us; speedup vs baseline: 1.6956x; 1.6956x over previous
//
#include <hip/hip_runtime.h>
#include <stdint.h>

typedef __bf16 bf16x8 __attribute__((ext_vector_type(8)));
typedef float  floatx4 __attribute__((ext_vector_type(4)));

#define T_LEN 512
#define BT    4       // batch rows per block -> 128 blocks; rows live at tile rows {0,4,8,12}
#define NTHR  512     // 8 waves; waves 0-3 = layer0 (+x staging), waves 4-7 = layer1
#define XS    72      // xb row stride (bf16)
#define HBS   136     // h bf16 LDS row stride
#define HFS   132     // final h1 fp32 row stride

#if __has_builtin(__builtin_amdgcn_exp2f)
#define EXP2(x) __builtin_amdgcn_exp2f(x)
#else
#define EXP2(x) exp2f(x)
#endif

#define MFMA(a,b,c) __builtin_amdgcn_mfma_f32_16x16x32_bf16((a),(b),(c),0,0,0)

__device__ __forceinline__ float sigm(float x) {
    return __builtin_amdgcn_rcpf(1.f + EXP2(-1.4426950408889634f * x));
}
__device__ __forceinline__ float tanh_fast(float x) {
    return 2.f * __builtin_amdgcn_rcpf(1.f + EXP2(-2.8853900817779268f * x)) - 1.f;
}
__device__ __forceinline__ float gru_h(float pr, float pz, float pin, float phn, float hp) {
    const float r = sigm(pr), z = sigm(pz);
    const float n = tanh_fast(pin + r * phn);
    return n + z * (hp - n);
}
__device__ __forceinline__ bf16x8 wfrag(const float* W, int ldk, int row, int k0) {
    const float* p = W + (size_t)row * ldk + k0;
    bf16x8 r;
    #pragma unroll
    for (int j = 0; j < 8; ++j) r[j] = (__bf16)p[j];
    return r;
}

// One block = 4 batch rows at MFMA tile rows {0,4,8,12} (= quad*4+0): gate math
// touches only acc[0] with ALL 64 lanes active -> 12 trans-instr/wave/step.
// Dead tile rows stay zero (harmless: they only affect dead C rows).
// Wave-specialized (waves 0-3 L0 + x staging, 4-7 L1); layer-lag, 1 barrier/step.
// x prefetch is 2 steps deep, issued right AFTER the barrier so the barrier's
// vmcnt drain never waits on it.
__global__ __launch_bounds__(NTHR, 2) void gru_fused(
    const float* __restrict__ x,
    const float* __restrict__ Wih0, const float* __restrict__ Whh0,
    const float* __restrict__ bih0, const float* __restrict__ bhh0,
    const float* __restrict__ Wih1, const float* __restrict__ Whh1,
    const float* __restrict__ bih1, const float* __restrict__ bhh1,
    const float* __restrict__ Wfc,  const float* __restrict__ bfc,
    float* __restrict__ out)
{
    __shared__ __align__(16) __bf16 xb[2][16 * XS];
    __shared__ __align__(16) __bf16 h0b[2][16 * HBS];
    __shared__ __align__(16) __bf16 h1b[2][16 * HBS];
    __shared__ __align__(16) float  hfin[16 * HFS];

    const int tid  = threadIdx.x;
    const int lane = tid & 63;
    const int ln16 = lane & 15;
    const int quad = lane >> 4;
    const int q8   = quad * 8;
    const int wave = tid >> 6;            // 0..7
    const int wv   = wave & 3;            // index within the layer group
    const int brow = blockIdx.x * BT;

    for (int i = tid; i < 16 * HBS; i += NTHR) {
        h0b[0][i] = (__bf16)0.f; h0b[1][i] = (__bf16)0.f;
        h1b[0][i] = (__bf16)0.f; h1b[1][i] = (__bf16)0.f;
    }
    for (int i = tid; i < 16 * XS; i += NTHR) {   // dead x rows stay zero
        xb[0][i] = (__bf16)0.f; xb[1][i] = (__bf16)0.f;
    }

    float hf[2] = {0.f, 0.f};             // h state: tile row quad*4, col per tile

    if (wave < 4) {
        // ============ layer-0 waves: cols [32wv,32wv+32), plus x staging ============
        float bR[2], bZ[2], bI[2], bH[2];
        bf16x8 wI[2][3][2], wH[2][3][4];
        #pragma unroll
        for (int t2 = 0; t2 < 2; ++t2) {
            const int c = wv * 32 + t2 * 16 + ln16;
            bR[t2] = bih0[c]       + bhh0[c];
            bZ[t2] = bih0[128 + c] + bhh0[128 + c];
            bI[t2] = bih0[256 + c];
            bH[t2] = bhh0[256 + c];
            #pragma unroll
            for (int g = 0; g < 3; ++g) {
                const int row = g * 128 + c;
                #pragma unroll
                for (int q = 0; q < 2; ++q) wI[t2][g][q] = wfrag(Wih0, 64, row, q * 32 + q8);
                #pragma unroll
                for (int q = 0; q < 4; ++q) wH[t2][g][q] = wfrag(Whh0, 128, row, q * 32 + q8);
            }
        }

        // staging: threads 0..255 (waves 0-3), batch row b=tid>>6, col=tid&63
        const int sb  = tid >> 6;         // 0..3
        const int sc  = tid & 63;
        const float* xp = x + (size_t)(brow + sb) * T_LEN * 64 + sc;
        float vx0 = xp[0];                              // x(0)
        float vx1 = xp[64];                             // x(1)

        for (int tt = 0; tt <= T_LEN; ++tt) {
            xb[tt & 1][(sb * 4) * XS + sc] = (__bf16)vx0;   // tile row 4b
            __syncthreads();              // barrier 1 of 1 per iter
            vx0 = vx1;                    // rotate; load below is 1 full step
            {                             // ahead of the barrier that drains it
                const int tnext = (tt + 2 < T_LEN) ? tt + 2 : T_LEN - 1;
                vx1 = xp[(size_t)tnext * 64];
            }

            if (tt < T_LEN) {
                const int R = tt & 1, Wn = R ^ 1;
                bf16x8 ax0 = *(const bf16x8*)&xb[R][ln16 * XS + q8];
                bf16x8 ax1 = *(const bf16x8*)&xb[R][ln16 * XS + 32 + q8];
                bf16x8 ah[4];
                #pragma unroll
                for (int q = 0; q < 4; ++q)
                    ah[q] = *(const bf16x8*)&h0b[R][ln16 * HBS + q * 32 + q8];

                #pragma unroll
                for (int t2 = 0; t2 < 2; ++t2) {
                    floatx4 aR  = {bR[t2], bR[t2], bR[t2], bR[t2]};
                    floatx4 aZ  = {bZ[t2], bZ[t2], bZ[t2], bZ[t2]};
                    floatx4 aNi = {bI[t2], bI[t2], bI[t2], bI[t2]};
                    floatx4 aNh = {bH[t2], bH[t2], bH[t2], bH[t2]};
                    aR  = MFMA(ax0, wI[t2][0][0], aR);  aR  = MFMA(ax1, wI[t2][0][1], aR);
                    aZ  = MFMA(ax0, wI[t2][1][0], aZ);  aZ  = MFMA(ax1, wI[t2][1][1], aZ);
                    aNi = MFMA(ax0, wI[t2][2][0], aNi); aNi = MFMA(ax1, wI[t2][2][1], aNi);
                    #pragma unroll
                    for (int q = 0; q < 4; ++q) {
                        aR  = MFMA(ah[q], wH[t2][0][q], aR);
                        aZ  = MFMA(ah[q], wH[t2][1][q], aZ);
                        aNh = MFMA(ah[q], wH[t2][2][q], aNh);
                    }
                    // gate math: tile row quad*4 (acc[0]) only -- all lanes valid
                    const int cc = wv * 32 + t2 * 16 + ln16;
                    const float h = gru_h(aR[0], aZ[0], aNi[0], aNh[0], hf[t2]);
                    hf[t2] = h;
                    h0b[Wn][(quad * 4) * HBS + cc] = (__bf16)h;
                }
            }
        }
    } else {
        // ================= layer-1 waves: cols [32wv,32wv+32) =================
        float bR[2], bZ[2], bI[2], bH[2];
        bf16x8 wI[2][3][4], wH[2][3][4];
        #pragma unroll
        for (int t2 = 0; t2 < 2; ++t2) {
            const int c = wv * 32 + t2 * 16 + ln16;
            bR[t2] = bih1[c]       + bhh1[c];
            bZ[t2] = bih1[128 + c] + bhh1[128 + c];
            bI[t2] = bih1[256 + c];
            bH[t2] = bhh1[256 + c];
            #pragma unroll
            for (int g = 0; g < 3; ++g) {
                const int row = g * 128 + c;
                #pragma unroll
                for (int q = 0; q < 4; ++q) {
                    wI[t2][g][q] = wfrag(Wih1, 128, row, q * 32 + q8);
                    wH[t2][g][q] = wfrag(Whh1, 128, row, q * 32 + q8);
                }
            }
        }

        for (int tt = 0; tt <= T_LEN; ++tt) {
            __syncthreads();              // barrier 1 of 1 per iter (count matches L0)

            if (tt > 0) {                 // L1 step tt-1
                const int R = tt & 1, Wn = R ^ 1;
                bf16x8 ah[4], a1[4];
                #pragma unroll
                for (int q = 0; q < 4; ++q) {
                    ah[q] = *(const bf16x8*)&h0b[R][ln16 * HBS + q * 32 + q8];
                    a1[q] = *(const bf16x8*)&h1b[R][ln16 * HBS + q * 32 + q8];
                }

                #pragma unroll
                for (int t2 = 0; t2 < 2; ++t2) {
                    floatx4 aR  = {bR[t2], bR[t2], bR[t2], bR[t2]};
                    floatx4 aZ  = {bZ[t2], bZ[t2], bZ[t2], bZ[t2]};
                    floatx4 aNi = {bI[t2], bI[t2], bI[t2], bI[t2]};
                    floatx4 aNh = {bH[t2], bH[t2], bH[t2], bH[t2]};
                    #pragma unroll
                    for (int q = 0; q < 4; ++q) {
                        aR  = MFMA(ah[q], wI[t2][0][q], aR);
                        aZ  = MFMA(ah[q], wI[t2][1][q], aZ);
                        aNi = MFMA(ah[q], wI[t2][2][q], aNi);
                    }
                    #pragma unroll
                    for (int q = 0; q < 4; ++q) {
                        aR  = MFMA(a1[q], wH[t2][0][q], aR);
                        aZ  = MFMA(a1[q], wH[t2][1][q], aZ);
                        aNh = MFMA(a1[q], wH[t2][2][q], aNh);
                    }
                    const int cc = wv * 32 + t2 * 16 + ln16;
                    const float h = gru_h(aR[0], aZ[0], aNi[0], aNh[0], hf[t2]);
                    hf[t2] = h;
                    h1b[Wn][(quad * 4) * HBS + cc] = (__bf16)h;
                }
            }
        }

        // publish final h1 (valid tile rows quad*4) for the FC epilogue
        #pragma unroll
        for (int t2 = 0; t2 < 2; ++t2)
            hfin[(quad * 4) * HFS + wv * 32 + t2 * 16 + ln16] = hf[t2];
    }

    __syncthreads();
    // final FC: out[b] = h1(T-1)[b,:] . Wfc + bfc  (tile rows 0,4,8,12)
    {
        const int row = tid >> 5, l = tid & 31;     // row 0..15
        if ((row & 3) == 0) {
            float s = 0.f;
            #pragma unroll
            for (int k = 0; k < 4; ++k)
                s += hfin[row * HFS + l + 32 * k] * Wfc[l + 32 * k];
            #pragma unroll
            for (int d = 16; d >= 1; d >>= 1) s += __shfl_down(s, d, 32);
            if (l == 0) out[brow + (row >> 2)] = s + bfc[0];
        }
    }
}

extern "C" void kernel_launch(void* const* d_in, const int* in_sizes, int n_in,
                              void* d_out, int out_size, void* d_ws, size_t ws_size,
                              hipStream_t stream) {
    const float* x    = (const float*)d_in[0];
    const float* Wih0 = (const float*)d_in[1];
    const float* Whh0 = (const float*)d_in[2];
    const float* bih0 = (const float*)d_in[3];
    const float* bhh0 = (const float*)d_in[4];
    const float* Wih1 = (const float*)d_in[5];
    const float* Whh1 = (const float*)d_in[6];
    const float* bih1 = (const float*)d_in[7];
    const float* bhh1 = (const float*)d_in[8];
    const float* Wfc  = (const float*)d_in[9];
    const float* bfc  = (const float*)d_in[10];
    float* out = (float*)d_out;

    hipLaunchKernelGGL(gru_fused, dim3(512 / BT), dim3(NTHR), 0, stream,
                       x, Wih0, Whh0, bih0, bhh0, Wih1, Whh1, bih1, bhh1, Wfc, bfc, out);
}

// Round 10
// 420.132 us; speedup vs baseline: 2.5736x; 1.5178x over previous
//
#include <hip/hip_runtime.h>
#include <stdint.h>

typedef __bf16 bf16x8 __attribute__((ext_vector_type(8)));
typedef float  floatx4 __attribute__((ext_vector_type(4)));
typedef int    i32x4  __attribute__((ext_vector_type(4)));

#define T_LEN 512
#define BT    4       // batch rows per block -> 128 blocks; rows at tile rows {0,4,8,12}
#define NTHR  512     // 8 waves; waves 0-3 = layer0 (+x staging), waves 4-7 = layer1
#define XS    72      // xb row stride (bf16)
#define HIS   144     // h int8 LDS row stride (bytes; (144/4)%32=4 -> 2-way alias, free)
#define HFS   132     // final h1 fp32 row stride

#if __has_builtin(__builtin_amdgcn_exp2f)
#define EXP2(x) __builtin_amdgcn_exp2f(x)
#else
#define EXP2(x) exp2f(x)
#endif

#define MFMA_BF(a,b,c)  __builtin_amdgcn_mfma_f32_16x16x32_bf16((a),(b),(c),0,0,0)
#define MFMA_I8(a,b,c)  __builtin_amdgcn_mfma_i32_16x16x64_i8((a),(b),(c),0,0,0)

// quantization: h -> q*1/127 ; w -> q*1/254 (|w| clamped at 0.5)
#define L2E   1.4426950408889634f
#define S_RZ  (-L2E / (254.f * 127.f))        // i32 -> -log2e * preact
#define S_N   (-2.f * L2E / (254.f * 127.f))  // i32 -> -2*log2e * preact

__device__ __forceinline__ float rcpf(float x) { return __builtin_amdgcn_rcpf(x); }

// bf16 B-fragment with folded scale (x-side weights)
__device__ __forceinline__ bf16x8 wfrag_bf(const float* W, int ldk, int row, int k0, float scale) {
    const float* p = W + (size_t)row * ldk + k0;
    bf16x8 r;
    #pragma unroll
    for (int j = 0; j < 8; ++j) r[j] = (__bf16)(p[j] * scale);
    return r;
}
// int8 B-fragment: 16 weights along K, quantized *254, clamped +-127, packed LE
__device__ __forceinline__ i32x4 wfrag_i8(const float* W, int ldk, int row, int k0) {
    const float* p = W + (size_t)row * ldk + k0;
    i32x4 r;
    #pragma unroll
    for (int d = 0; d < 4; ++d) {
        uint32_t dw = 0;
        #pragma unroll
        for (int j = 0; j < 4; ++j) {
            float q = __builtin_rintf(p[d * 4 + j] * 254.f);
            q = fminf(127.f, fmaxf(-127.f, q));
            dw |= ((uint32_t)((int)q & 0xff)) << (8 * j);
        }
        r[d] = (int)dw;
    }
    return r;
}

// One block = 4 batch rows at tile rows {0,4,8,12} (=quad*4): gate math on acc[0]
// only, all 64 lanes active. Wave-specialized (0-3: L0 + x staging; 4-7: L1).
// Hidden-state GEMMs in int8 K=64 MFMA (1.63x bf16 rate, frags/LDS reads halve);
// x-side stays bf16. Sigmoid/tanh log2e scales folded into dequant consts/biases.
// Layer-lag, ONE barrier/step, 2-deep x prefetch issued after the barrier.
__global__ __launch_bounds__(NTHR, 2) void gru_fused(
    const float* __restrict__ x,
    const float* __restrict__ Wih0, const float* __restrict__ Whh0,
    const float* __restrict__ bih0, const float* __restrict__ bhh0,
    const float* __restrict__ Wih1, const float* __restrict__ Whh1,
    const float* __restrict__ bih1, const float* __restrict__ bhh1,
    const float* __restrict__ Wfc,  const float* __restrict__ bfc,
    float* __restrict__ out)
{
    __shared__ __align__(16) __bf16      xb[2][16 * XS];
    __shared__ __align__(16) signed char h0i[2][16 * HIS];
    __shared__ __align__(16) signed char h1i[2][16 * HIS];
    __shared__ __align__(16) float       hfin[16 * HFS];

    const int tid  = threadIdx.x;
    const int lane = tid & 63;
    const int ln16 = lane & 15;
    const int quad = lane >> 4;
    const int q8   = quad * 8;        // bf16 k-offset (elements)
    const int q16  = quad * 16;       // int8 k-offset (bytes)
    const int wave = tid >> 6;        // 0..7
    const int wv   = wave & 3;
    const int brow = blockIdx.x * BT;

    for (int i = tid; i < 16 * HIS; i += NTHR) {
        h0i[0][i] = 0; h0i[1][i] = 0;
        h1i[0][i] = 0; h1i[1][i] = 0;
    }
    for (int i = tid; i < 16 * XS; i += NTHR) {   // dead x rows stay zero
        xb[0][i] = (__bf16)0.f; xb[1][i] = (__bf16)0.f;
    }

    float hf[2] = {0.f, 0.f};

    if (wave < 4) {
        // ===== layer-0: cols [32wv,32wv+32); x-side bf16, hidden int8 =====
        float bRZ[2], bNi[2], bNh[2];
        bf16x8 wI[2][3][2];           // x-side, scale-folded (12 frags)
        i32x4  wH[2][3][2];           // hidden int8 K=64 (12 frags)
        #pragma unroll
        for (int t2 = 0; t2 < 2; ++t2) {
            const int c = wv * 32 + t2 * 16 + ln16;
            bRZ[t2] = 0.f;            // per-gate below
            bNi[t2] = -2.f * L2E * bih0[256 + c];
            bNh[t2] = -2.f * L2E * bhh0[256 + c];
            #pragma unroll
            for (int g = 0; g < 3; ++g) {
                const int row = g * 128 + c;
                const float sc = (g == 2) ? (-2.f * L2E) : (-L2E);
                #pragma unroll
                for (int q = 0; q < 2; ++q) {
                    wI[t2][g][q] = wfrag_bf(Wih0, 64, row, q * 32 + q8, sc);
                    wH[t2][g][q] = wfrag_i8(Whh0, 128, row, q * 64 + q16);
                }
            }
        }
        float bR[2], bZ[2];
        #pragma unroll
        for (int t2 = 0; t2 < 2; ++t2) {
            const int c = wv * 32 + t2 * 16 + ln16;
            bR[t2] = -L2E * (bih0[c] + bhh0[c]);
            bZ[t2] = -L2E * (bih0[128 + c] + bhh0[128 + c]);
        }

        // staging: threads 0..255, batch row tid>>6, col tid&63
        const int sb = tid >> 6, sc = tid & 63;
        const float* xp = x + (size_t)(brow + sb) * T_LEN * 64 + sc;
        float vx0 = xp[0];
        float vx1 = xp[64];

        for (int tt = 0; tt <= T_LEN; ++tt) {
            xb[tt & 1][(sb * 4) * XS + sc] = (__bf16)vx0;
            __syncthreads();          // the ONLY barrier per iter
            vx0 = vx1;
            {
                const int tnext = (tt + 2 < T_LEN) ? tt + 2 : T_LEN - 1;
                vx1 = xp[(size_t)tnext * 64];
            }

            if (tt < T_LEN) {
                const int R = tt & 1, Wn = R ^ 1;
                bf16x8 ax0 = *(const bf16x8*)&xb[R][ln16 * XS + q8];
                bf16x8 ax1 = *(const bf16x8*)&xb[R][ln16 * XS + 32 + q8];
                i32x4 ah[2];
                #pragma unroll
                for (int q = 0; q < 2; ++q)
                    ah[q] = *(const i32x4*)&h0i[R][ln16 * HIS + q * 64 + q16];

                #pragma unroll
                for (int t2 = 0; t2 < 2; ++t2) {
                    floatx4 fR  = {bR[t2],  bR[t2],  bR[t2],  bR[t2]};
                    floatx4 fZ  = {bZ[t2],  bZ[t2],  bZ[t2],  bZ[t2]};
                    floatx4 fNi = {bNi[t2], bNi[t2], bNi[t2], bNi[t2]};
                    i32x4 cR = {0,0,0,0}, cZ = {0,0,0,0}, cNh = {0,0,0,0};
                    fR  = MFMA_BF(ax0, wI[t2][0][0], fR);  fR  = MFMA_BF(ax1, wI[t2][0][1], fR);
                    fZ  = MFMA_BF(ax0, wI[t2][1][0], fZ);  fZ  = MFMA_BF(ax1, wI[t2][1][1], fZ);
                    fNi = MFMA_BF(ax0, wI[t2][2][0], fNi); fNi = MFMA_BF(ax1, wI[t2][2][1], fNi);
                    #pragma unroll
                    for (int q = 0; q < 2; ++q) {
                        cR  = MFMA_I8(ah[q], wH[t2][0][q], cR);
                        cZ  = MFMA_I8(ah[q], wH[t2][1][q], cZ);
                        cNh = MFMA_I8(ah[q], wH[t2][2][q], cNh);
                    }
                    // gate math (tile row quad*4 = acc[0]); scales pre-folded
                    const float pr  = fmaf((float)cR[0],  S_RZ, fR[0]);
                    const float pz  = fmaf((float)cZ[0],  S_RZ, fZ[0]);
                    const float phn = fmaf((float)cNh[0], S_N,  bNh[t2]);
                    const float r = rcpf(1.f + EXP2(pr));
                    const float z = rcpf(1.f + EXP2(pz));
                    const float n = 2.f * rcpf(1.f + EXP2(fmaf(r, phn, fNi[0]))) - 1.f;
                    const float h = n + z * (hf[t2] - n);
                    hf[t2] = h;
                    const int cc = wv * 32 + t2 * 16 + ln16;
                    h0i[Wn][(quad * 4) * HIS + cc] =
                        (signed char)(int)__builtin_rintf(h * 127.f);
                }
            }
        }
    } else {
        // ===== layer-1: cols [32wv,32wv+32); all int8 (shared h0/h1 scale) =====
        float bRZ1[2], bNi1[2], bNh1[2];
        i32x4 wI[2][3][2], wH[2][3][2];   // 24 frags = 96 VGPRs
        #pragma unroll
        for (int t2 = 0; t2 < 2; ++t2) {
            const int c = wv * 32 + t2 * 16 + ln16;
            bRZ1[t2] = 0.f;
            bNi1[t2] = -2.f * L2E * bih1[256 + c];
            bNh1[t2] = -2.f * L2E * bhh1[256 + c];
            #pragma unroll
            for (int g = 0; g < 3; ++g) {
                const int row = g * 128 + c;
                #pragma unroll
                for (int q = 0; q < 2; ++q) {
                    wI[t2][g][q] = wfrag_i8(Wih1, 128, row, q * 64 + q16);
                    wH[t2][g][q] = wfrag_i8(Whh1, 128, row, q * 64 + q16);
                }
            }
        }
        float bR1[2], bZ1[2];
        #pragma unroll
        for (int t2 = 0; t2 < 2; ++t2) {
            const int c = wv * 32 + t2 * 16 + ln16;
            bR1[t2] = -L2E * (bih1[c] + bhh1[c]);
            bZ1[t2] = -L2E * (bih1[128 + c] + bhh1[128 + c]);
        }

        for (int tt = 0; tt <= T_LEN; ++tt) {
            __syncthreads();          // matches L0's barrier count
            if (tt > 0) {             // L1 step tt-1
                const int R = tt & 1, Wn = R ^ 1;
                i32x4 ah[2], a1[2];
                #pragma unroll
                for (int q = 0; q < 2; ++q) {
                    ah[q] = *(const i32x4*)&h0i[R][ln16 * HIS + q * 64 + q16];
                    a1[q] = *(const i32x4*)&h1i[R][ln16 * HIS + q * 64 + q16];
                }
                #pragma unroll
                for (int t2 = 0; t2 < 2; ++t2) {
                    i32x4 cR = {0,0,0,0}, cZ = {0,0,0,0};
                    i32x4 cNi = {0,0,0,0}, cNh = {0,0,0,0};
                    #pragma unroll
                    for (int q = 0; q < 2; ++q) {     // input side (h0)
                        cR  = MFMA_I8(ah[q], wI[t2][0][q], cR);
                        cZ  = MFMA_I8(ah[q], wI[t2][1][q], cZ);
                        cNi = MFMA_I8(ah[q], wI[t2][2][q], cNi);
                    }
                    #pragma unroll
                    for (int q = 0; q < 2; ++q) {     // hidden side (h1), same scale
                        cR  = MFMA_I8(a1[q], wH[t2][0][q], cR);
                        cZ  = MFMA_I8(a1[q], wH[t2][1][q], cZ);
                        cNh = MFMA_I8(a1[q], wH[t2][2][q], cNh);
                    }
                    const float pr  = fmaf((float)cR[0],  S_RZ, bR1[t2]);
                    const float pz  = fmaf((float)cZ[0],  S_RZ, bZ1[t2]);
                    const float pin = fmaf((float)cNi[0], S_N,  bNi1[t2]);
                    const float phn = fmaf((float)cNh[0], S_N,  bNh1[t2]);
                    const float r = rcpf(1.f + EXP2(pr));
                    const float z = rcpf(1.f + EXP2(pz));
                    const float n = 2.f * rcpf(1.f + EXP2(fmaf(r, phn, pin))) - 1.f;
                    const float h = n + z * (hf[t2] - n);
                    hf[t2] = h;
                    const int cc = wv * 32 + t2 * 16 + ln16;
                    h1i[Wn][(quad * 4) * HIS + cc] =
                        (signed char)(int)__builtin_rintf(h * 127.f);
                }
            }
        }
        // publish final h1 (fp32 state, not quantized) for the FC epilogue
        #pragma unroll
        for (int t2 = 0; t2 < 2; ++t2)
            hfin[(quad * 4) * HFS + wv * 32 + t2 * 16 + ln16] = hf[t2];
    }

    __syncthreads();
    // final FC: out[b] = h1(T-1)[b,:] . Wfc + bfc  (tile rows 0,4,8,12)
    {
        const int row = tid >> 5, l = tid & 31;
        if ((row & 3) == 0) {
            float s = 0.f;
            #pragma unroll
            for (int k = 0; k < 4; ++k)
                s += hfin[row * HFS + l + 32 * k] * Wfc[l + 32 * k];
            #pragma unroll
            for (int d = 16; d >= 1; d >>= 1) s += __shfl_down(s, d, 32);
            if (l == 0) out[brow + (row >> 2)] = s + bfc[0];
        }
    }
}

extern "C" void kernel_launch(void* const* d_in, const int* in_sizes, int n_in,
                              void* d_out, int out_size, void* d_ws, size_t ws_size,
                              hipStream_t stream) {
    const float* x    = (const float*)d_in[0];
    const float* Wih0 = (const float*)d_in[1];
    const float* Whh0 = (const float*)d_in[2];
    const float* bih0 = (const float*)d_in[3];
    const float* bhh0 = (const float*)d_in[4];
    const float* Wih1 = (const float*)d_in[5];
    const float* Whh1 = (const float*)d_in[6];
    const float* bih1 = (const float*)d_in[7];
    const float* bhh1 = (const float*)d_in[8];
    const float* Wfc  = (const float*)d_in[9];
    const float* bfc  = (const float*)d_in[10];
    float* out = (float*)d_out;

    hipLaunchKernelGGL(gru_fused, dim3(512 / BT), dim3(NTHR), 0, stream,
                       x, Wih0, Whh0, bih0, bhh0, Wih1, Whh1, bih1, bhh1, Wfc, bfc, out);
}